// Round 14
// baseline (4365.370 us; speedup 1.0000x reference)
//
#include <hip/hip_runtime.h>

#define HIDDEN 256
#define TENC 336
#define HORIZ 168
#define BSZ 1024
#define BH (BSZ*HIDDEN)   // f16 elements per h snapshot (512 KiB)

typedef _Float16 f16;
typedef f16 f16x8 __attribute__((ext_vector_type(8)));
typedef float f32x4 __attribute__((ext_vector_type(4)));
typedef unsigned int u32;
typedef unsigned short u16;
typedef unsigned long long u64;

// ---- workspace layout (R9-identical) ----
#define H0_OFF 0                        // 3 slots x 512K
#define H1_OFF (3*BH*2)                 // 2 slots x 512K
#define PP_OFF (H1_OFF + 2*BH*2)        // 2 slots x [1024][16] f32
#define F0_OFF (PP_OFF + 2*BSZ*16*4)    // 1024 member lines x 64B
#define F1_OFF (F0_OFF + 1024*64)
#define WS_TOTAL (F1_OFF + 1024*64)

// ---- dynamic LDS (96 KiB < proven 102400 launch ceiling) ----
#define LDS_W0  0        // Whh0 slice fragments, 32KB
#define LDS_W1I 32768    // Wih1 slice fragments, 32KB
#define LDS_W1H 65536    // Whh1 slice fragments, 32KB
#define LDS_TOTAL 98304

__device__ __forceinline__ float sigm(float x){ return 1.0f/(1.0f+__expf(-x)); }
__device__ __forceinline__ float tanh_f(float x){ return 2.0f/(1.0f+__expf(-2.0f*x)) - 1.0f; }

// ---- proven agent-scope primitives (R1/R6/R9) ----
__device__ __forceinline__ u64 ald64(const void* p){
  return __hip_atomic_load((const u64*)p, __ATOMIC_RELAXED, __HIP_MEMORY_SCOPE_AGENT);
}
__device__ __forceinline__ u32 ald32(const u32* p){
  return __hip_atomic_load(p, __ATOMIC_RELAXED, __HIP_MEMORY_SCOPE_AGENT);
}
__device__ __forceinline__ void ast32(u32* p, u32 v){
  __hip_atomic_store(p, v, __ATOMIC_RELAXED, __HIP_MEMORY_SCOPE_AGENT);
}
__device__ __forceinline__ void ast64(u64* p, u64 v){
  __hip_atomic_store(p, v, __ATOMIC_RELAXED, __HIP_MEMORY_SCOPE_AGENT);
}

// W-fragment from f32 weights: lane holds W[grow(16-dim idx = lane&15)][k..k+7]
__device__ __forceinline__ f16x8 loadWfrag(const float* W, int grow, int k){
  const float* p = W + grow*HIDDEN + k;
  float4 lo = *(const float4*)p;
  float4 hi = *(const float4*)(p+4);
  f16x8 r;
  r[0]=(f16)lo.x; r[1]=(f16)lo.y; r[2]=(f16)lo.z; r[3]=(f16)lo.w;
  r[4]=(f16)hi.x; r[5]=(f16)hi.y; r[6]=(f16)hi.z; r[7]=(f16)hi.w;
  return r;
}

// per-wave poll: lanes 0..15 poll f0 member lines (stride 64 u32 = 256B),
// lanes 16..31 poll f1. s_sleep backoff. R9 semantics, bit-identical.
__device__ __forceinline__ void pollw2(const u32* f0, u32 t0, const u32* f1, u32 t1, int lane){
  const u32* sp = nullptr; u32 tgt = 0;
  if (lane < 16){ sp = f0 + lane*64; tgt = t0; }
  else if (f1 != nullptr && lane < 32){ sp = f1 + (lane-16)*64; tgt = t1; }
  for (int it = 0; it < (1<<20); ++it){
    u32 v = 0xffffffffu;
    if (sp) v = ald32(sp);
    if (__all((int)(v >= tgt))) break;
    __builtin_amdgcn_s_sleep(1);
  }
}

// per-wave release: drain this wave's (uncached) h-stores, then one flag store
__device__ __forceinline__ void sigw(u32* line, u32 v, int lane){
  asm volatile("s_waitcnt vmcnt(0)" ::: "memory");
  if (lane == 0) ast32(line, v);
}

// load 8 h-fragments (now the MFMA B-operand) — R9-identical layout & code
__device__ __forceinline__ void loadA8n(f16x8* a, const f16* slotu, int lane){
  const int r16 = (lane & 15) * 16;
  const int h8  = ((lane >> 4) & 1) * 8;
  const int jb  = lane >> 5;
  #pragma unroll
  for (int kt=0; kt<8; ++kt){
    const f16* q = slotu + (kt*2 + jb)*256 + r16 + h8;
    union { u64 w[2]; f16x8 v; } u;
    u.w[0] = ald64(q); u.w[1] = ald64(q+4);
    a[kt] = u.v;
  }
}

// MFMA with W-fragments from LDS as the A-OPERAND (transposed-gates):
// D[gatedim][batch]: col=lane&15 = batch row, row=(lane>>4)*4+q = dim
__device__ __forceinline__ void mm4W(f32x4* acc, const f16x8* a, const char* WL, int lane){
  #pragma unroll
  for (int kt=0; kt<8; ++kt){
    #pragma unroll
    for (int n=0; n<4; ++n){
      f16x8 wf = *(const f16x8*)(WL + ((n*8+kt)*64 + lane)*16);
      acc[n] = __builtin_amdgcn_mfma_f32_16x16x32_f16(wf, a[kt], acc[n], 0,0,0);
    }
  }
}

// transposed cell: thread owns batch row (lane&15) and 4 dims (hq*4+q),
// with all 4 gates in acc[n][q].
__device__ __forceinline__ void cellT(const f32x4* acc, const float bv[4][4],
                                      const float wxv[4][4], float xr,
                                      float* cst, float* h4){
  #pragma unroll
  for (int q=0; q<4; ++q){
    float pi = acc[0][q] + bv[0][q] + xr*wxv[0][q];
    float pf = acc[1][q] + bv[1][q] + xr*wxv[1][q];
    float pg = acc[2][q] + bv[2][q] + xr*wxv[2][q];
    float po = acc[3][q] + bv[3][q] + xr*wxv[3][q];
    float i = sigm(pi), f = sigm(pf), gg = tanh_f(pg), o = sigm(po);
    cst[q] = f*cst[q] + i*gg;
    h4[q] = o*tanh_f(cst[q]);
  }
}

// direct h-store: pack 4 f16 -> ONE u64 into [16 rows][16 dims] chunk.
// byte addr = row*32 + hq*8 ; wave covers the full 512B chunk (full lines).
__device__ __forceinline__ void storeH2(f16* chunk, const float* h4, int lane){
  u64 v = 0;
  #pragma unroll
  for (int q=0; q<4; ++q){
    u16 b = __builtin_bit_cast(u16, (f16)h4[q]);
    v |= (u64)b << (16*q);
  }
  ast64((u64*)(chunk + (lane&15)*16 + (lane>>4)*4), v);
}

struct P {
  const float *x;
  const float *eWih0,*eWhh0,*eBih0,*eBhh0,*eWih1,*eWhh1,*eBih1,*eBhh1;
  const float *dWih0,*dWhh0,*dBih0,*dBhh0,*dWih1,*dWhh1,*dBih1,*dBhh1;
  const float *fcW,*fcB;
  float* out;
  char* ws;
};

__global__ void initk(char* ws){
  u32* p = (u32*)ws;
  size_t total = (size_t)WS_TOTAL / 4;
  for (size_t k = (size_t)blockIdx.x*blockDim.x + threadIdx.x; k < total;
       k += (size_t)gridDim.x*blockDim.x) p[k] = 0u;
}

__global__ __launch_bounds__(512) void lstm_main(P p){
  const int tid  = threadIdx.x;
  const int lane = tid & 63;
  const int w    = tid >> 6;
  const int chain= w >> 2;         // 0 = L0 chain, 1 = L1 chain
  const int v    = w & 3;          // row-quarter unit / staging gate
  const int blk  = blockIdx.x;
  const int g    = blk & 15;       // row group
  const int j    = blk >> 4;       // member (16 dims)
  const int unit = g*4 + v;
  const int row  = g*64 + v*16 + (lane & 15);   // this thread's batch row
  const int hq   = lane >> 4;                   // dim quarter 0..3

  extern __shared__ __align__(16) char smem[];
  char* sW0  = smem + LDS_W0;
  char* sW1i = smem + LDS_W1I;
  char* sW1h = smem + LDS_W1H;

  f16*   h0buf = (f16*)(p.ws + H0_OFF);
  f16*   h1buf = (f16*)(p.ws + H1_OFF);
  float* ppart = (float*)(p.ws + PP_OFF);
  u32*   F0    = (u32*)(p.ws + F0_OFF);
  u32*   F1    = (u32*)(p.ws + F1_OFF);
  const u32* pF0 = F0 + ((g*16 + 0)*4 + v)*16;   // member stride = 64 u32
  const u32* pF1 = F1 + ((g*16 + 0)*4 + v)*16;
  u32* myF0 = F0 + ((g*16 + j)*4 + v)*16;
  u32* myF1 = F1 + ((g*16 + j)*4 + v)*16;

  float cst[4] = {0.f,0.f,0.f,0.f};
  float bv[4][4], wxv[4][4], fcwv[4];
  float fcb = 0.f;

  // ---- stage encoder weights into LDS (R9-identical layout) ----
  if (chain == 0){
    #pragma unroll
    for (int kt=0; kt<8; ++kt)
      *(f16x8*)(sW0 + ((v*8+kt)*64 + lane)*16) =
        loadWfrag(p.eWhh0, v*256 + j*16 + (lane&15), kt*32 + 8*hq);
    #pragma unroll
    for (int n=0; n<4; ++n)
      #pragma unroll
      for (int q=0; q<4; ++q){
        int dim = j*16 + hq*4 + q;
        wxv[n][q] = p.eWih0[n*256 + dim];
        bv[n][q]  = p.eBih0[n*256 + dim] + p.eBhh0[n*256 + dim];
      }
  } else {
    #pragma unroll
    for (int kt=0; kt<8; ++kt){
      *(f16x8*)(sW1i + ((v*8+kt)*64 + lane)*16) =
        loadWfrag(p.eWih1, v*256 + j*16 + (lane&15), kt*32 + 8*hq);
      *(f16x8*)(sW1h + ((v*8+kt)*64 + lane)*16) =
        loadWfrag(p.eWhh1, v*256 + j*16 + (lane&15), kt*32 + 8*hq);
    }
    #pragma unroll
    for (int n=0; n<4; ++n)
      #pragma unroll
      for (int q=0; q<4; ++q){
        int dim = j*16 + hq*4 + q;
        wxv[n][q] = 0.f;
        bv[n][q]  = p.eBih1[n*256 + dim] + p.eBhh1[n*256 + dim];
      }
  }
  __syncthreads();

  // ================= ENCODER (chains run concurrently) =====================
  if (chain == 0){
    for (int r = 0; r < TENC; ++r){
      float xr = p.x[row*TENC + r];
      pollw2(pF0, (u32)r, pF1, (r>=2)?(u32)(r-2):0u, lane);
      f16x8 a[8];
      loadA8n(a, h0buf + ((r+2)%3)*BH + unit*4096, lane);
      f32x4 acc[4] = {{0,0,0,0},{0,0,0,0},{0,0,0,0},{0,0,0,0}};
      mm4W(acc, a, sW0, lane);
      float h4[4];
      cellT(acc, bv, wxv, xr, cst, h4);
      storeH2(h0buf + (r%3)*BH + unit*4096 + j*256, h4, lane);
      sigw(myF0, (u32)(r+1), lane);
    }
  } else {
    for (int r = 0; r < TENC; ++r){
      // lagged own-chain part first: Whh1 * h1(r-1)
      pollw2(pF1, (u32)r, nullptr, 0, lane);
      f16x8 a1[8];
      loadA8n(a1, h1buf + ((r+1)&1)*BH + unit*4096, lane);
      f32x4 acc[4] = {{0,0,0,0},{0,0,0,0},{0,0,0,0},{0,0,0,0}};
      mm4W(acc, a1, sW1h, lane);
      // fresh cross-chain part: Wih1 * h0(r)
      pollw2(pF0, (u32)(r+1), nullptr, 0, lane);
      f16x8 a0[8];
      loadA8n(a0, h0buf + (r%3)*BH + unit*4096, lane);
      mm4W(acc, a0, sW1i, lane);
      float h4[4];
      cellT(acc, bv, wxv, 0.f, cst, h4);
      storeH2(h1buf + (r&1)*BH + unit*4096 + j*256, h4, lane);
      sigw(myF1, (u32)(r+1), lane);
    }
  }

  // ---- swap to decoder weights ----
  __syncthreads();
  if (chain == 0){
    #pragma unroll
    for (int kt=0; kt<8; ++kt)
      *(f16x8*)(sW0 + ((v*8+kt)*64 + lane)*16) =
        loadWfrag(p.dWhh0, v*256 + j*16 + (lane&15), kt*32 + 8*hq);
    #pragma unroll
    for (int n=0; n<4; ++n)
      #pragma unroll
      for (int q=0; q<4; ++q){
        int dim = j*16 + hq*4 + q;
        wxv[n][q] = p.dWih0[n*256 + dim];
        bv[n][q]  = p.dBih0[n*256 + dim] + p.dBhh0[n*256 + dim];
      }
    fcb = p.fcB[0];
  } else {
    #pragma unroll
    for (int kt=0; kt<8; ++kt){
      *(f16x8*)(sW1i + ((v*8+kt)*64 + lane)*16) =
        loadWfrag(p.dWih1, v*256 + j*16 + (lane&15), kt*32 + 8*hq);
      *(f16x8*)(sW1h + ((v*8+kt)*64 + lane)*16) =
        loadWfrag(p.dWhh1, v*256 + j*16 + (lane&15), kt*32 + 8*hq);
    }
    #pragma unroll
    for (int n=0; n<4; ++n)
      #pragma unroll
      for (int q=0; q<4; ++q){
        int dim = j*16 + hq*4 + q;
        wxv[n][q] = 0.f;
        bv[n][q]  = p.dBih1[n*256 + dim] + p.dBhh1[n*256 + dim];
        if (n == 0) fcwv[q] = p.fcW[dim];
      }
  }
  __syncthreads();

  // ================= DECODER (ping-pong between chains) ====================
  if (chain == 0){
    for (int t = 0; t < HORIZ; ++t){
      // own-chain h0(t-1) first: hoist Whh0 MFMA off the fresh-pp path
      pollw2(pF0, (u32)(336+t), nullptr, 0, lane);
      f16x8 a[8];
      loadA8n(a, h0buf + ((335+t)%3)*BH + unit*4096, lane);
      f32x4 acc[4] = {{0,0,0,0},{0,0,0,0},{0,0,0,0},{0,0,0,0}};
      mm4W(acc, a, sW0, lane);
      // fresh dependency: pp(t-1) from chain1
      pollw2(pF1, (t==0)?335u:(u32)(336+t), nullptr, 0, lane);
      float inp;
      if (t == 0){
        inp = p.x[row*TENC + (TENC-1)];
      } else {
        const float* ps = ppart + ((t-1)&1)*BSZ*16 + row*16 + hq*4;
        u64 w0 = ald64(ps), w1 = ald64(ps+2);
        float s = __builtin_bit_cast(float,(u32)(w0 & 0xffffffffull))
                + __builtin_bit_cast(float,(u32)(w0 >> 32))
                + __builtin_bit_cast(float,(u32)(w1 & 0xffffffffull))
                + __builtin_bit_cast(float,(u32)(w1 >> 32));
        s += __shfl_xor(s, 16); s += __shfl_xor(s, 32);
        inp = s + fcb;
      }
      float h4[4];
      cellT(acc, bv, wxv, inp, cst, h4);
      storeH2(h0buf + ((336+t)%3)*BH + unit*4096 + j*256, h4, lane);
      if (t > 0 && j == 0 && lane < 16) p.out[row*HORIZ + (t-1)] = inp;
      sigw(myF0, (u32)(337+t), lane);
    }
    // final column: pred(167)
    if (j == 0){
      pollw2(pF1, 504u, nullptr, 0, lane);
      const float* ps = ppart + (167&1)*BSZ*16 + row*16 + hq*4;
      u64 w0 = ald64(ps), w1 = ald64(ps+2);
      float s = __builtin_bit_cast(float,(u32)(w0 & 0xffffffffull))
              + __builtin_bit_cast(float,(u32)(w0 >> 32))
              + __builtin_bit_cast(float,(u32)(w1 & 0xffffffffull))
              + __builtin_bit_cast(float,(u32)(w1 >> 32));
      s += __shfl_xor(s, 16); s += __shfl_xor(s, 32);
      if (lane < 16) p.out[row*HORIZ + (HORIZ-1)] = s + fcb;
    }
  } else {
    for (int t = 0; t < HORIZ; ++t){
      // lagged own-chain part first: Whh1 * h1(t-1)
      pollw2(pF1, (u32)(336+t), nullptr, 0, lane);
      f16x8 a1[8];
      loadA8n(a1, h1buf + ((t+1)&1)*BH + unit*4096, lane);
      f32x4 acc[4] = {{0,0,0,0},{0,0,0,0},{0,0,0,0},{0,0,0,0}};
      mm4W(acc, a1, sW1h, lane);
      // fresh: h0(t) from chain0
      pollw2(pF0, (u32)(337+t), nullptr, 0, lane);
      f16x8 a0[8];
      loadA8n(a0, h0buf + ((336+t)%3)*BH + unit*4096, lane);
      mm4W(acc, a0, sW1i, lane);
      float h4[4];
      cellT(acc, bv, wxv, 0.f, cst, h4);
      storeH2(h1buf + (t&1)*BH + unit*4096 + j*256, h4, lane);
      // pred partial over this member's 16 dims for this thread's row
      float s = fcwv[0]*h4[0] + fcwv[1]*h4[1] + fcwv[2]*h4[2] + fcwv[3]*h4[3];
      s += __shfl_xor(s, 16); s += __shfl_xor(s, 32);
      if (lane < 16)
        ast32((u32*)(ppart + (t&1)*BSZ*16 + row*16 + j), __builtin_bit_cast(u32, s));
      sigw(myF1, (u32)(337+t), lane);
    }
  }
}

extern "C" void kernel_launch(void* const* d_in, const int* in_sizes, int n_in,
                              void* d_out, int out_size, void* d_ws, size_t ws_size,
                              hipStream_t stream) {
  (void)in_sizes; (void)n_in; (void)out_size;
  if (ws_size < (size_t)WS_TOTAL) return;  // fail visibly (poisoned output)

  P prm;
  prm.x     = (const float*)d_in[0];
  prm.eWih0 = (const float*)d_in[1];  prm.eWhh0 = (const float*)d_in[2];
  prm.eBih0 = (const float*)d_in[3];  prm.eBhh0 = (const float*)d_in[4];
  prm.eWih1 = (const float*)d_in[5];  prm.eWhh1 = (const float*)d_in[6];
  prm.eBih1 = (const float*)d_in[7];  prm.eBhh1 = (const float*)d_in[8];
  prm.dWih0 = (const float*)d_in[9];  prm.dWhh0 = (const float*)d_in[10];
  prm.dBih0 = (const float*)d_in[11]; prm.dBhh0 = (const float*)d_in[12];
  prm.dWih1 = (const float*)d_in[13]; prm.dWhh1 = (const float*)d_in[14];
  prm.dBih1 = (const float*)d_in[15]; prm.dBhh1 = (const float*)d_in[16];
  prm.fcW   = (const float*)d_in[17]; prm.fcB   = (const float*)d_in[18];
  prm.out   = (float*)d_out;
  prm.ws    = (char*)d_ws;

  hipLaunchKernelGGL(initk, dim3(256), dim3(256), 0, stream, (char*)d_ws);

  hipFuncSetAttribute((const void*)lstm_main,
                      hipFuncAttributeMaxDynamicSharedMemorySize, LDS_TOTAL);
  void* args[] = { &prm };
  hipLaunchCooperativeKernel((const void*)lstm_main, dim3(256), dim3(512),
                             args, LDS_TOTAL, stream);
}

// Round 15
// 4312.909 us; speedup vs baseline: 1.0122x; 1.0122x over previous
//
#include <hip/hip_runtime.h>

#define HIDDEN 256
#define TENC 336
#define HORIZ 168
#define BSZ 1024
#define BH (BSZ*HIDDEN)   // f16 elements per h snapshot (512 KiB)

typedef _Float16 f16;
typedef f16 f16x8 __attribute__((ext_vector_type(8)));
typedef float f32x4 __attribute__((ext_vector_type(4)));
typedef unsigned int u32;
typedef unsigned short u16;
typedef unsigned long long u64;

// ---- workspace layout (R9-identical) ----
#define H0_OFF 0                        // 3 slots x 512K
#define H1_OFF (3*BH*2)                 // 2 slots x 512K
#define PP_OFF (H1_OFF + 2*BH*2)        // 2 slots x [1024][16] f32
#define F0_OFF (PP_OFF + 2*BSZ*16*4)    // 1024 member lines x 64B
#define F1_OFF (F0_OFF + 1024*64)
#define WS_TOTAL (F1_OFF + 1024*64)

// ---- dynamic LDS (96 KiB < proven 102400 launch ceiling) ----
#define LDS_W0  0        // Whh0 slice fragments, 32KB
#define LDS_W1I 32768    // Wih1 slice fragments, 32KB
#define LDS_W1H 65536    // Whh1 slice fragments, 32KB
#define LDS_TOTAL 98304

__device__ __forceinline__ float sigm(float x){ return 1.0f/(1.0f+__expf(-x)); }
__device__ __forceinline__ float tanh_f(float x){ return 2.0f/(1.0f+__expf(-2.0f*x)) - 1.0f; }

// ---- proven agent-scope primitives (R1/R6/R9) ----
__device__ __forceinline__ u64 ald64(const void* p){
  return __hip_atomic_load((const u64*)p, __ATOMIC_RELAXED, __HIP_MEMORY_SCOPE_AGENT);
}
__device__ __forceinline__ u32 ald32(const u32* p){
  return __hip_atomic_load(p, __ATOMIC_RELAXED, __HIP_MEMORY_SCOPE_AGENT);
}
__device__ __forceinline__ void ast32(u32* p, u32 v){
  __hip_atomic_store(p, v, __ATOMIC_RELAXED, __HIP_MEMORY_SCOPE_AGENT);
}
__device__ __forceinline__ void ast64(u64* p, u64 v){
  __hip_atomic_store(p, v, __ATOMIC_RELAXED, __HIP_MEMORY_SCOPE_AGENT);
}

// W-fragment from f32 weights: lane holds W[grow(16-dim idx = lane&15)][k..k+7]
__device__ __forceinline__ f16x8 loadWfrag(const float* W, int grow, int k){
  const float* p = W + grow*HIDDEN + k;
  float4 lo = *(const float4*)p;
  float4 hi = *(const float4*)(p+4);
  f16x8 r;
  r[0]=(f16)lo.x; r[1]=(f16)lo.y; r[2]=(f16)lo.z; r[3]=(f16)lo.w;
  r[4]=(f16)hi.x; r[5]=(f16)hi.y; r[6]=(f16)hi.z; r[7]=(f16)hi.w;
  return r;
}

// per-wave COMBINED poll: lanes 0..15 poll f0 member lines (stride 64 u32),
// lanes 16..31 poll f1 CONCURRENTLY. s_sleep backoff. R9 semantics.
__device__ __forceinline__ void pollw2(const u32* f0, u32 t0, const u32* f1, u32 t1, int lane){
  const u32* sp = nullptr; u32 tgt = 0;
  if (lane < 16){ sp = f0 + lane*64; tgt = t0; }
  else if (f1 != nullptr && lane < 32){ sp = f1 + (lane-16)*64; tgt = t1; }
  for (int it = 0; it < (1<<20); ++it){
    u32 v = 0xffffffffu;
    if (sp) v = ald32(sp);
    if (__all((int)(v >= tgt))) break;
    __builtin_amdgcn_s_sleep(1);
  }
}

// per-wave release: drain this wave's (uncached) h-stores, then one flag store
__device__ __forceinline__ void sigw(u32* line, u32 v, int lane){
  asm volatile("s_waitcnt vmcnt(0)" ::: "memory");
  if (lane == 0) ast32(line, v);
}

// load 8 h-fragments (MFMA B-operand) — R9-identical layout & code
__device__ __forceinline__ void loadA8n(f16x8* a, const f16* slotu, int lane){
  const int r16 = (lane & 15) * 16;
  const int h8  = ((lane >> 4) & 1) * 8;
  const int jb  = lane >> 5;
  #pragma unroll
  for (int kt=0; kt<8; ++kt){
    const f16* q = slotu + (kt*2 + jb)*256 + r16 + h8;
    union { u64 w[2]; f16x8 v; } u;
    u.w[0] = ald64(q); u.w[1] = ald64(q+4);
    a[kt] = u.v;
  }
}

// MFMA with W-fragments from LDS as the A-OPERAND (transposed-gates):
// D[gatedim][batch]: col=lane&15 = batch row, row=(lane>>4)*4+q = dim
__device__ __forceinline__ void mm4W(f32x4* acc, const f16x8* a, const char* WL, int lane){
  #pragma unroll
  for (int kt=0; kt<8; ++kt){
    #pragma unroll
    for (int n=0; n<4; ++n){
      f16x8 wf = *(const f16x8*)(WL + ((n*8+kt)*64 + lane)*16);
      acc[n] = __builtin_amdgcn_mfma_f32_16x16x32_f16(wf, a[kt], acc[n], 0,0,0);
    }
  }
}

// transposed cell: thread owns batch row (lane&15) and 4 dims (hq*4+q),
// with all 4 gates in acc[n][q].
__device__ __forceinline__ void cellT(const f32x4* acc, const float bv[4][4],
                                      const float wxv[4][4], float xr,
                                      float* cst, float* h4){
  #pragma unroll
  for (int q=0; q<4; ++q){
    float pi = acc[0][q] + bv[0][q] + xr*wxv[0][q];
    float pf = acc[1][q] + bv[1][q] + xr*wxv[1][q];
    float pg = acc[2][q] + bv[2][q] + xr*wxv[2][q];
    float po = acc[3][q] + bv[3][q] + xr*wxv[3][q];
    float i = sigm(pi), f = sigm(pf), gg = tanh_f(pg), o = sigm(po);
    cst[q] = f*cst[q] + i*gg;
    h4[q] = o*tanh_f(cst[q]);
  }
}

// direct h-store: pack 4 f16 -> ONE u64 into [16 rows][16 dims] chunk.
__device__ __forceinline__ void storeH2(f16* chunk, const float* h4, int lane){
  u64 v = 0;
  #pragma unroll
  for (int q=0; q<4; ++q){
    u16 b = __builtin_bit_cast(u16, (f16)h4[q]);
    v |= (u64)b << (16*q);
  }
  ast64((u64*)(chunk + (lane&15)*16 + (lane>>4)*4), v);
}

struct P {
  const float *x;
  const float *eWih0,*eWhh0,*eBih0,*eBhh0,*eWih1,*eWhh1,*eBih1,*eBhh1;
  const float *dWih0,*dWhh0,*dBih0,*dBhh0,*dWih1,*dWhh1,*dBih1,*dBhh1;
  const float *fcW,*fcB;
  float* out;
  char* ws;
};

__global__ void initk(char* ws){
  u32* p = (u32*)ws;
  size_t total = (size_t)WS_TOTAL / 4;
  for (size_t k = (size_t)blockIdx.x*blockDim.x + threadIdx.x; k < total;
       k += (size_t)gridDim.x*blockDim.x) p[k] = 0u;
}

__global__ __launch_bounds__(512) void lstm_main(P p){
  const int tid  = threadIdx.x;
  const int lane = tid & 63;
  const int w    = tid >> 6;
  const int chain= w >> 2;         // 0 = L0 chain, 1 = L1 chain
  const int v    = w & 3;          // row-quarter unit / staging gate
  const int blk  = blockIdx.x;
  const int g    = blk & 15;       // row group
  const int j    = blk >> 4;       // member (16 dims)
  const int unit = g*4 + v;
  const int row  = g*64 + v*16 + (lane & 15);   // this thread's batch row
  const int hq   = lane >> 4;                   // dim quarter 0..3

  extern __shared__ __align__(16) char smem[];
  char* sW0  = smem + LDS_W0;
  char* sW1i = smem + LDS_W1I;
  char* sW1h = smem + LDS_W1H;

  f16*   h0buf = (f16*)(p.ws + H0_OFF);
  f16*   h1buf = (f16*)(p.ws + H1_OFF);
  float* ppart = (float*)(p.ws + PP_OFF);
  u32*   F0    = (u32*)(p.ws + F0_OFF);
  u32*   F1    = (u32*)(p.ws + F1_OFF);
  const u32* pF0 = F0 + ((g*16 + 0)*4 + v)*16;   // member stride = 64 u32
  const u32* pF1 = F1 + ((g*16 + 0)*4 + v)*16;
  u32* myF0 = F0 + ((g*16 + j)*4 + v)*16;
  u32* myF1 = F1 + ((g*16 + j)*4 + v)*16;

  float cst[4] = {0.f,0.f,0.f,0.f};
  float bv[4][4], wxv[4][4], fcwv[4];
  float fcb = 0.f;

  // ---- stage encoder weights into LDS ----
  if (chain == 0){
    #pragma unroll
    for (int kt=0; kt<8; ++kt)
      *(f16x8*)(sW0 + ((v*8+kt)*64 + lane)*16) =
        loadWfrag(p.eWhh0, v*256 + j*16 + (lane&15), kt*32 + 8*hq);
    #pragma unroll
    for (int n=0; n<4; ++n)
      #pragma unroll
      for (int q=0; q<4; ++q){
        int dim = j*16 + hq*4 + q;
        wxv[n][q] = p.eWih0[n*256 + dim];
        bv[n][q]  = p.eBih0[n*256 + dim] + p.eBhh0[n*256 + dim];
      }
  } else {
    #pragma unroll
    for (int kt=0; kt<8; ++kt){
      *(f16x8*)(sW1i + ((v*8+kt)*64 + lane)*16) =
        loadWfrag(p.eWih1, v*256 + j*16 + (lane&15), kt*32 + 8*hq);
      *(f16x8*)(sW1h + ((v*8+kt)*64 + lane)*16) =
        loadWfrag(p.eWhh1, v*256 + j*16 + (lane&15), kt*32 + 8*hq);
    }
    #pragma unroll
    for (int n=0; n<4; ++n)
      #pragma unroll
      for (int q=0; q<4; ++q){
        int dim = j*16 + hq*4 + q;
        wxv[n][q] = 0.f;
        bv[n][q]  = p.eBih1[n*256 + dim] + p.eBhh1[n*256 + dim];
      }
  }
  __syncthreads();

  // ================= ENCODER (chains run concurrently) =====================
  if (chain == 0){
    for (int r = 0; r < TENC; ++r){
      float xr = p.x[row*TENC + r];
      pollw2(pF0, (u32)r, pF1, (r>=2)?(u32)(r-2):0u, lane);
      f16x8 a[8];
      loadA8n(a, h0buf + ((r+2)%3)*BH + unit*4096, lane);
      f32x4 acc[4] = {{0,0,0,0},{0,0,0,0},{0,0,0,0},{0,0,0,0}};
      mm4W(acc, a, sW0, lane);
      float h4[4];
      cellT(acc, bv, wxv, xr, cst, h4);
      storeH2(h0buf + (r%3)*BH + unit*4096 + j*256, h4, lane);
      sigw(myF0, (u32)(r+1), lane);
    }
  } else {
    for (int r = 0; r < TENC; ++r){
      // COMBINED poll: h0(r) fresh (lanes 0-15) & h1(r-1) lagged (lanes 16-31)
      pollw2(pF0, (u32)(r+1), pF1, (u32)r, lane);
      f16x8 a0[8], a1[8];
      loadA8n(a0, h0buf + (r%3)*BH + unit*4096, lane);
      loadA8n(a1, h1buf + ((r+1)&1)*BH + unit*4096, lane);
      f32x4 acc[4] = {{0,0,0,0},{0,0,0,0},{0,0,0,0},{0,0,0,0}};
      mm4W(acc, a0, sW1i, lane);  // Wih1 * h0(r)
      mm4W(acc, a1, sW1h, lane);  // Whh1 * h1(r-1)
      float h4[4];
      cellT(acc, bv, wxv, 0.f, cst, h4);
      storeH2(h1buf + (r&1)*BH + unit*4096 + j*256, h4, lane);
      sigw(myF1, (u32)(r+1), lane);
    }
  }

  // ---- swap to decoder weights ----
  __syncthreads();
  if (chain == 0){
    #pragma unroll
    for (int kt=0; kt<8; ++kt)
      *(f16x8*)(sW0 + ((v*8+kt)*64 + lane)*16) =
        loadWfrag(p.dWhh0, v*256 + j*16 + (lane&15), kt*32 + 8*hq);
    #pragma unroll
    for (int n=0; n<4; ++n)
      #pragma unroll
      for (int q=0; q<4; ++q){
        int dim = j*16 + hq*4 + q;
        wxv[n][q] = p.dWih0[n*256 + dim];
        bv[n][q]  = p.dBih0[n*256 + dim] + p.dBhh0[n*256 + dim];
      }
    fcb = p.fcB[0];
  } else {
    #pragma unroll
    for (int kt=0; kt<8; ++kt){
      *(f16x8*)(sW1i + ((v*8+kt)*64 + lane)*16) =
        loadWfrag(p.dWih1, v*256 + j*16 + (lane&15), kt*32 + 8*hq);
      *(f16x8*)(sW1h + ((v*8+kt)*64 + lane)*16) =
        loadWfrag(p.dWhh1, v*256 + j*16 + (lane&15), kt*32 + 8*hq);
    }
    #pragma unroll
    for (int n=0; n<4; ++n)
      #pragma unroll
      for (int q=0; q<4; ++q){
        int dim = j*16 + hq*4 + q;
        wxv[n][q] = 0.f;
        bv[n][q]  = p.dBih1[n*256 + dim] + p.dBhh1[n*256 + dim];
        if (n == 0) fcwv[q] = p.fcW[dim];
      }
  }
  __syncthreads();

  // ================= DECODER (ping-pong between chains) ====================
  if (chain == 0){
    for (int t = 0; t < HORIZ; ++t){
      // COMBINED poll: h0(t-1) (lanes 0-15) & {h1,pp}(t-1) (lanes 16-31)
      pollw2(pF0, (u32)(336+t), pF1, (t==0)?335u:(u32)(336+t), lane);
      float inp;
      if (t == 0){
        inp = p.x[row*TENC + (TENC-1)];
      } else {
        const float* ps = ppart + ((t-1)&1)*BSZ*16 + row*16 + hq*4;
        u64 w0 = ald64(ps), w1 = ald64(ps+2);
        float s = __builtin_bit_cast(float,(u32)(w0 & 0xffffffffull))
                + __builtin_bit_cast(float,(u32)(w0 >> 32))
                + __builtin_bit_cast(float,(u32)(w1 & 0xffffffffull))
                + __builtin_bit_cast(float,(u32)(w1 >> 32));
        s += __shfl_xor(s, 16); s += __shfl_xor(s, 32);
        inp = s + fcb;
      }
      f16x8 a[8];
      loadA8n(a, h0buf + ((335+t)%3)*BH + unit*4096, lane);
      f32x4 acc[4] = {{0,0,0,0},{0,0,0,0},{0,0,0,0},{0,0,0,0}};
      mm4W(acc, a, sW0, lane);
      float h4[4];
      cellT(acc, bv, wxv, inp, cst, h4);
      storeH2(h0buf + ((336+t)%3)*BH + unit*4096 + j*256, h4, lane);
      if (t > 0 && j == 0 && lane < 16) p.out[row*HORIZ + (t-1)] = inp;
      sigw(myF0, (u32)(337+t), lane);
    }
    // final column: pred(167)
    if (j == 0){
      pollw2(pF1, 504u, nullptr, 0, lane);
      const float* ps = ppart + (167&1)*BSZ*16 + row*16 + hq*4;
      u64 w0 = ald64(ps), w1 = ald64(ps+2);
      float s = __builtin_bit_cast(float,(u32)(w0 & 0xffffffffull))
              + __builtin_bit_cast(float,(u32)(w0 >> 32))
              + __builtin_bit_cast(float,(u32)(w1 & 0xffffffffull))
              + __builtin_bit_cast(float,(u32)(w1 >> 32));
      s += __shfl_xor(s, 16); s += __shfl_xor(s, 32);
      if (lane < 16) p.out[row*HORIZ + (HORIZ-1)] = s + fcb;
    }
  } else {
    for (int t = 0; t < HORIZ; ++t){
      // COMBINED poll: h0(t) fresh (lanes 0-15) & h1(t-1) lagged (lanes 16-31)
      pollw2(pF0, (u32)(337+t), pF1, (u32)(336+t), lane);
      f16x8 a0[8], a1[8];
      loadA8n(a0, h0buf + ((336+t)%3)*BH + unit*4096, lane);
      loadA8n(a1, h1buf + ((t+1)&1)*BH + unit*4096, lane);
      f32x4 acc[4] = {{0,0,0,0},{0,0,0,0},{0,0,0,0},{0,0,0,0}};
      mm4W(acc, a0, sW1i, lane);  // dWih1 * h0(t)
      mm4W(acc, a1, sW1h, lane);  // dWhh1 * h1(t-1)
      float h4[4];
      cellT(acc, bv, wxv, 0.f, cst, h4);
      storeH2(h1buf + (t&1)*BH + unit*4096 + j*256, h4, lane);
      // pred partial over this member's 16 dims for this thread's row
      float s = fcwv[0]*h4[0] + fcwv[1]*h4[1] + fcwv[2]*h4[2] + fcwv[3]*h4[3];
      s += __shfl_xor(s, 16); s += __shfl_xor(s, 32);
      if (lane < 16)
        ast32((u32*)(ppart + (t&1)*BSZ*16 + row*16 + j), __builtin_bit_cast(u32, s));
      sigw(myF1, (u32)(337+t), lane);
    }
  }
}

extern "C" void kernel_launch(void* const* d_in, const int* in_sizes, int n_in,
                              void* d_out, int out_size, void* d_ws, size_t ws_size,
                              hipStream_t stream) {
  (void)in_sizes; (void)n_in; (void)out_size;
  if (ws_size < (size_t)WS_TOTAL) return;  // fail visibly (poisoned output)

  P prm;
  prm.x     = (const float*)d_in[0];
  prm.eWih0 = (const float*)d_in[1];  prm.eWhh0 = (const float*)d_in[2];
  prm.eBih0 = (const float*)d_in[3];  prm.eBhh0 = (const float*)d_in[4];
  prm.eWih1 = (const float*)d_in[5];  prm.eWhh1 = (const float*)d_in[6];
  prm.eBih1 = (const float*)d_in[7];  prm.eBhh1 = (const float*)d_in[8];
  prm.dWih0 = (const float*)d_in[9];  prm.dWhh0 = (const float*)d_in[10];
  prm.dBih0 = (const float*)d_in[11]; prm.dBhh0 = (const float*)d_in[12];
  prm.dWih1 = (const float*)d_in[13]; prm.dWhh1 = (const float*)d_in[14];
  prm.dBih1 = (const float*)d_in[15]; prm.dBhh1 = (const float*)d_in[16];
  prm.fcW   = (const float*)d_in[17]; prm.fcB   = (const float*)d_in[18];
  prm.out   = (float*)d_out;
  prm.ws    = (char*)d_ws;

  hipLaunchKernelGGL(initk, dim3(256), dim3(256), 0, stream, (char*)d_ws);

  hipFuncSetAttribute((const void*)lstm_main,
                      hipFuncAttributeMaxDynamicSharedMemorySize, LDS_TOTAL);
  void* args[] = { &prm };
  hipLaunchCooperativeKernel((const void*)lstm_main, dim3(256), dim3(512),
                             args, LDS_TOTAL, stream);
}